// Round 1
// baseline (35.590 us; speedup 1.0000x reference)
//
#include <hip/hip_runtime.h>
#include <math.h>

// 32 fixed taps from the problem definition (TAPS_INT), as exact fp32 values.
__device__ __constant__ const float TAPS[32] = {
    -12.f,  -34.f,  -56.f,  -42.f,   18.f,  120.f,  260.f,  380.f,
    400.f,  290.f,   60.f, -210.f, -430.f, -500.f, -380.f, -120.f,
    180.f,  430.f,  540.f,  480.f,  280.f,   20.f, -220.f, -370.f,
   -400.f, -310.f, -150.f,   10.f,  120.f,  160.f,  130.f,   60.f
};

#define SCALE_INV (1.0f / 65536.0f)
#define OPT 16  // outputs per thread

__global__ __launch_bounds__(256)
void fir32_kernel(const float* __restrict__ x, float* __restrict__ y, int n) {
    const long chunk = (long)blockIdx.x * blockDim.x + threadIdx.x;
    const long n0 = chunk * OPT;
    if (n0 >= n) return;

    // Fast path: a full chunk of 16 outputs, all with n >= 32 and all loads
    // in-bounds (window is x[n0-32 .. n0+15], 48 floats, 64B-aligned).
    if (n0 >= 32 && n0 + OPT <= n) {
        float w[48];
        const float4* src = reinterpret_cast<const float4*>(x + (n0 - 32));
        #pragma unroll
        for (int v = 0; v < 12; ++v) {
            float4 t = src[v];
            w[4 * v + 0] = t.x;
            w[4 * v + 1] = t.y;
            w[4 * v + 2] = t.z;
            w[4 * v + 3] = t.w;
        }

        float acc[OPT];
        #pragma unroll
        for (int j = 0; j < OPT; ++j) {
            float a = 0.0f;
            #pragma unroll
            for (int k = 0; k < 32; ++k) {
                // acc[n0+j] = sum_k x[n0+j-k] * taps[k];  x[n0+j-k] == w[32+j-k]
                a = fmaf(w[32 + j - k], TAPS[k], a);
            }
            acc[j] = floorf(a * SCALE_INV);
        }

        float4* dst = reinterpret_cast<float4*>(y + n0);
        #pragma unroll
        for (int v = 0; v < 4; ++v) {
            float4 t;
            t.x = acc[4 * v + 0];
            t.y = acc[4 * v + 1];
            t.z = acc[4 * v + 2];
            t.w = acc[4 * v + 3];
            dst[v] = t;
        }
        return;
    }

    // Slow path: head chunks (outputs with n < 32 are defined as 0) and any
    // ragged tail. Scalar, bounds-checked.
    for (int j = 0; j < OPT; ++j) {
        const long m = n0 + j;
        if (m >= n) break;
        float r = 0.0f;
        if (m >= 32) {
            float a = 0.0f;
            for (int k = 0; k < 32; ++k) {
                a = fmaf(x[m - k], TAPS[k], a);  // m-k >= 1, in bounds
            }
            r = floorf(a * SCALE_INV);
        }
        y[m] = r;
    }
}

extern "C" void kernel_launch(void* const* d_in, const int* in_sizes, int n_in,
                              void* d_out, int out_size, void* d_ws, size_t ws_size,
                              hipStream_t stream) {
    const float* x = (const float*)d_in[0];
    float* y = (float*)d_out;
    const int n = in_sizes[0];

    const long nchunks = ((long)n + OPT - 1) / OPT;
    const int block = 256;
    const long grid = (nchunks + block - 1) / block;

    fir32_kernel<<<dim3((unsigned)grid), dim3(block), 0, stream>>>(x, y, n);
}

// Round 2
// 29.413 us; speedup vs baseline: 1.2100x; 1.2100x over previous
//
#include <hip/hip_runtime.h>
#include <math.h>

// 32 fixed taps from the problem definition (TAPS_INT), as exact fp32 values.
__device__ __constant__ const float TAPS[32] = {
    -12.f,  -34.f,  -56.f,  -42.f,   18.f,  120.f,  260.f,  380.f,
    400.f,  290.f,   60.f, -210.f, -430.f, -500.f, -380.f, -120.f,
    180.f,  430.f,  540.f,  480.f,  280.f,   20.f, -220.f, -370.f,
   -400.f, -310.f, -150.f,   10.f,  120.f,  160.f,  130.f,   60.f
};

#define SCALE_INV (1.0f / 65536.0f)
#define TILE 4096
#define HALO 32
#define NF4_IN ((TILE + HALO) / 4)   // 1032 float4s staged per block
#define NF4_OUT (TILE / 4)           // 1024 float4s out per block

// XOR swizzle on float4 index: involution, 16B-alignment-preserving,
// balances every access pattern here to the 8-per-4-bank-group minimum.
__device__ __forceinline__ int swz(int q) { return q ^ ((q >> 3) & 7); }

__global__ __launch_bounds__(256)
void fir32_lds(const float* __restrict__ x, float* __restrict__ y, int n) {
    __shared__ float4 s_in[NF4_IN];
    __shared__ float4 s_out[NF4_OUT];

    const int tid = threadIdx.x;
    const long tile = (long)blockIdx.x * TILE;
    const long base4 = (tile - HALO) / 4;  // exact (tile-32 divisible by 4); -8 for block 0
    const long n4 = n >> 2;

    // ---- Phase 1: dense coalesced staging of x[tile-32 .. tile+4095] ----
    const float4* x4 = reinterpret_cast<const float4*>(x);
    #pragma unroll
    for (int v = 0; v < 5; ++v) {
        int f = v * 256 + tid;
        if (f < NF4_IN) {
            long i4 = base4 + f;
            float4 val = make_float4(0.f, 0.f, 0.f, 0.f);
            if (i4 >= 0 && i4 < n4) val = x4[i4];
            s_in[swz(f)] = val;
        }
    }
    __syncthreads();

    // ---- Phase 2: window from LDS, 512 unrolled FMAs ----
    float w[48];
    #pragma unroll
    for (int v = 0; v < 12; ++v) {
        int q = 4 * tid + v;
        float4 t = s_in[swz(q)];
        w[4 * v + 0] = t.x;
        w[4 * v + 1] = t.y;
        w[4 * v + 2] = t.z;
        w[4 * v + 3] = t.w;
    }

    const bool head = (blockIdx.x == 0 && tid < 2);  // outputs 0..31 are defined 0
    float acc[16];
    #pragma unroll
    for (int j = 0; j < 16; ++j) {
        float a = 0.0f;
        #pragma unroll
        for (int k = 0; k < 32; ++k) {
            // y[tile + tid*16 + j] needs x[m-k] == w[32 + j - k]
            a = fmaf(w[32 + j - k], TAPS[k], a);
        }
        float r = floorf(a * SCALE_INV);
        acc[j] = head ? 0.0f : r;
    }

    // ---- Phase 3: round-trip through LDS so global stores are dense ----
    #pragma unroll
    for (int v = 0; v < 4; ++v) {
        int q = 4 * tid + v;
        s_out[swz(q)] = make_float4(acc[4 * v + 0], acc[4 * v + 1],
                                    acc[4 * v + 2], acc[4 * v + 3]);
    }
    __syncthreads();

    float4* y4 = reinterpret_cast<float4*>(y) + (tile >> 2);
    #pragma unroll
    for (int v = 0; v < 4; ++v) {
        int f = v * 256 + tid;
        if (tile + 4L * f < n) y4[f] = s_out[swz(f)];
    }
}

extern "C" void kernel_launch(void* const* d_in, const int* in_sizes, int n_in,
                              void* d_out, int out_size, void* d_ws, size_t ws_size,
                              hipStream_t stream) {
    const float* x = (const float*)d_in[0];
    float* y = (float*)d_out;
    const int n = in_sizes[0];

    const int grid = (int)(((long)n + TILE - 1) / TILE);  // 4096 blocks for N=2^24
    fir32_lds<<<dim3(grid), dim3(256), 0, stream>>>(x, y, n);
}